// Round 6
// baseline (491.216 us; speedup 1.0000x reference)
//
#include <hip/hip_runtime.h>
#include <math.h>

#define LSEQ 2048
#define NB 2
#define HDIM 1024
#define NKV 128          // 2*HEAD_SIZE
#define MALL (NB*LSEQ)   // 4096
#define KSPLIT 4

typedef float vf4 __attribute__((ext_vector_type(4)));  // native vector: NT-storable

// ---------------- K1: seq_out partials = inputs @ Wp (K split in 4) --------
__global__ __launch_bounds__(256) void k1_gemm(const float* __restrict__ A,
                                               const float* __restrict__ Wp,
                                               float* __restrict__ Cp) {
    const int nt    = blockIdx.x & 1;
    const int split = blockIdx.x >> 1;
    const int m0 = blockIdx.y * 64;
    const int n0 = nt * 64;
    __shared__ float As[32][68];   // [k][m], pad 68 keeps float4 reads 16B-aligned
    __shared__ float Bs[32][64];   // [k][n]
    const int tid = threadIdx.x;
    const int tm = tid & 15;       // m quad
    const int tn = tid >> 4;       // n quad
    float acc[4][4] = {};
    for (int kc = 0; kc < 8; ++kc) {
        const int k0 = split*256 + kc*32;
        #pragma unroll
        for (int p = 0; p < 2; ++p) {
            int idx = tid + 256*p;          // 0..511
            int row = idx >> 3, kq = idx & 7;
            float4 a = *(const float4*)(A + (size_t)(m0+row)*HDIM + k0 + 4*kq);
            As[4*kq+0][row] = a.x;
            As[4*kq+1][row] = a.y;
            As[4*kq+2][row] = a.z;
            As[4*kq+3][row] = a.w;
        }
        #pragma unroll
        for (int p = 0; p < 2; ++p) {
            int idx = tid + 256*p;
            int r = idx >> 4, c = idx & 15;
            *(float4*)(&Bs[r][4*c]) = *(const float4*)(Wp + (size_t)(k0+r)*NKV + n0 + 4*c);
        }
        __syncthreads();
        #pragma unroll
        for (int kk = 0; kk < 32; ++kk) {
            float4 av = *(const float4*)(&As[kk][4*tm]);
            float4 bv = *(const float4*)(&Bs[kk][4*tn]);
            float aa[4] = {av.x, av.y, av.z, av.w};
            float bb[4] = {bv.x, bv.y, bv.z, bv.w};
            #pragma unroll
            for (int i = 0; i < 4; ++i)
                #pragma unroll
                for (int j = 0; j < 4; ++j)
                    acc[i][j] = fmaf(aa[i], bb[j], acc[i][j]);
        }
        __syncthreads();
    }
    float* outp = Cp + (size_t)split*MALL*NKV;
    #pragma unroll
    for (int i = 0; i < 4; ++i) {
        float4 v = make_float4(acc[i][0], acc[i][1], acc[i][2], acc[i][3]);
        *(float4*)(outp + (size_t)(m0 + 4*tm + i)*NKV + n0 + 4*tn) = v;
    }
}

// ---------------- K2: sum K-splits (+bp), RoPE, bias = seq@Wq/2 ------------
__global__ __launch_bounds__(64) void k2_rope_bias(const float* __restrict__ Cp,
        const float* __restrict__ bp, const float* __restrict__ Wq,
        const float* __restrict__ bq, float* __restrict__ qwout,
        float* __restrict__ kwout, float* __restrict__ biasQ,
        float* __restrict__ biasK) {
    const int row = blockIdx.x;         // 0..4095 (b*L + l)
    const int b = row >> 11;
    const int l = row & (LSEQ - 1);
    const int t = threadIdx.x;          // 0..63 ; lane t owns dims (2t, 2t+1)
    float x0 = bp[2*t], x1 = bp[2*t+1];
    #pragma unroll
    for (int s = 0; s < KSPLIT; ++s) {
        const float* r = Cp + (size_t)s*MALL*NKV + (size_t)row*NKV;
        x0 += r[2*t];
        x1 += r[2*t+1];
    }
    const int p = t & 31;               // pair index within head
    float inv = exp2f(-0.41524101186098287f * (float)p);  // 10000^(-p/32)
    float ang = (float)l * inv;
    float sn = sinf(ang), cs = cosf(ang);
    float y0 = x0*cs - x1*sn;
    float y1 = x1*cs + x0*sn;
    float* dst = (t < 32) ? (qwout + (size_t)row*64) : (kwout + (size_t)row*64);
    dst[2*p]   = y0;
    dst[2*p+1] = y1;
    float res = 0.f;
    for (int j = 0; j < 24; ++j) {
        float part = fmaf(x0, Wq[(2*t)*24 + j], x1 * Wq[(2*t+1)*24 + j]);
        #pragma unroll
        for (int off = 32; off > 0; off >>= 1)
            part += __shfl_xor(part, off);
        if (t == j) res = part;
    }
    if (t < 24) {
        float v = (res + bq[t]) * 0.5f;
        int h = t >> 1;
        float* bb = (t & 1) ? biasK : biasQ;
        bb[((size_t)b*12 + h)*LSEQ + l] = v;
    }
}

// ---------------- K3 v6: float4 NT bursts, loads-before-stores -------------
// grid (256, 2): x = 8 m-rows, y = b. 256 threads; half-wave (32 lanes) per
// m-row, lane l5 owns n-quad 4*l5 within a 128-n chunk (16 chunks).
// kw chunk double-buffered in 64 KB LDS, quad-XOR swizzle q^((r>>2)&15):
// conflict-free staging writes AND dot reads. Per chunk: dot -> prefetch
// next kw + 12 biasK float4 + mask (ALL loads issued before stores;
// sched_barrier pins order so in-order vmcnt never waits on stores) ->
// 12 NT float4 stores (1 KB/wave-instr = fill-kernel burst size) ->
// ds_write prefetch -> ONE lgkm-only barrier. Stores never drained in-loop.
__global__ __launch_bounds__(256, 2) void k3_scores(const float* __restrict__ qw,
        const float* __restrict__ kwv, const float* __restrict__ biasQ,
        const float* __restrict__ biasK, const int* __restrict__ mask,
        float* __restrict__ out) {
    extern __shared__ float kws[];       // 2 bufs x 128 n x 64 d = 64 KB
    const int m0  = blockIdx.x * 8;
    const int b   = blockIdx.y;
    const int tid = threadIdx.x;
    const int l5  = tid & 31;            // n-quad lane
    const int m   = m0 + (tid >> 5);     // one m-row per 32-lane group
    const int key = l5 & 15;             // read-side swizzle key = (row>>2)&15
    const size_t rowbase = (size_t)b * LSEQ;

    float4 q4[16];
    {
        const float4* qp = (const float4*)(qw + (rowbase + m)*64);
        #pragma unroll
        for (int j = 0; j < 16; ++j) q4[j] = qp[j];
    }
    float bqh[12];
    #pragma unroll
    for (int h = 0; h < 12; ++h) bqh[h] = biasQ[((size_t)b*12 + h)*LSEQ + m];
    const bool okm = mask[rowbase + m] != 0;

    // prologue: stage chunk 0 into buf 0 (coalesced loads, swizzled LDS writes)
    #pragma unroll
    for (int p = 0; p < 8; ++p) {
        int F = tid + 256*p;             // 2048 float4 per 128x64 chunk
        int r = F >> 4, q16 = F & 15;
        float4 v = *(const float4*)(kwv + (rowbase + r)*64 + 4*q16);
        *(float4*)(&kws[r*64 + 4*(q16 ^ ((r>>2)&15))]) = v;
    }
    asm volatile("s_waitcnt lgkmcnt(0)");
    __builtin_amdgcn_s_barrier();

    for (int c = 0; c < 16; ++c) {
        const int nb  = c * 128;
        const int cur = (c & 1) * 8192;  // 128*64 words per buffer
        const int n0  = nb + 4*l5;

        // 1. dot: q[m] . kw[n0..n0+3] from swizzled LDS (conflict-free b128)
        float4 a = {0.f, 0.f, 0.f, 0.f};
        const float* rb = kws + cur + 4*l5*64;   // chunk-local rows 4*l5..+3
        #pragma unroll
        for (int j = 0; j < 16; ++j) {
            const int col = 4*(j ^ key);
            float4 k0 = *(const float4*)(rb + col);          // row 4*l5+0
            float4 k1 = *(const float4*)(rb + 64  + col);    // row 4*l5+1
            float4 k2 = *(const float4*)(rb + 128 + col);    // row 4*l5+2
            float4 k3 = *(const float4*)(rb + 192 + col);    // row 4*l5+3
            float4 qv = q4[j];
            a.x = fmaf(qv.x,k0.x,fmaf(qv.y,k0.y,fmaf(qv.z,k0.z,fmaf(qv.w,k0.w,a.x))));
            a.y = fmaf(qv.x,k1.x,fmaf(qv.y,k1.y,fmaf(qv.z,k1.z,fmaf(qv.w,k1.w,a.y))));
            a.z = fmaf(qv.x,k2.x,fmaf(qv.y,k2.y,fmaf(qv.z,k2.z,fmaf(qv.w,k2.w,a.z))));
            a.w = fmaf(qv.x,k3.x,fmaf(qv.y,k3.y,fmaf(qv.z,k3.z,fmaf(qv.w,k3.w,a.w))));
        }
        a.x *= 0.125f; a.y *= 0.125f; a.z *= 0.125f; a.w *= 0.125f;

        // 2. ALL loads before any store (in-order vmcnt: later waits on these
        //    loads never require store completion)
        float4 pre[8];
        if (c < 15) {
            #pragma unroll
            for (int p = 0; p < 8; ++p) {
                int F = tid + 256*p;
                int r = F >> 4, q16 = F & 15;
                pre[p] = *(const float4*)(kwv + (rowbase + nb + 128 + r)*64 + 4*q16);
            }
        }
        float4 bkv[12];
        #pragma unroll
        for (int h = 0; h < 12; ++h)
            bkv[h] = *(const float4*)(biasK + ((size_t)b*12 + h)*LSEQ + n0);
        const int4 mq = *(const int4*)(mask + rowbase + n0);
        __builtin_amdgcn_sched_barrier(0);   // pin: loads above, stores below

        // 3. epilogue + 12 NT float4 stores (1 KB per wave-instruction)
        const bool ok0 = okm && (mq.x != 0);
        const bool ok1 = okm && (mq.y != 0);
        const bool ok2 = okm && (mq.z != 0);
        const bool ok3 = okm && (mq.w != 0);
        const float p0 = (m > n0+0) ? 1e12f : 0.f;
        const float p1 = (m > n0+1) ? 1e12f : 0.f;
        const float p2 = (m > n0+2) ? 1e12f : 0.f;
        const float p3 = (m > n0+3) ? 1e12f : 0.f;
        float* op = out + ((size_t)b*12*LSEQ + (size_t)m)*LSEQ + n0;
        #pragma unroll
        for (int h = 0; h < 12; ++h) {
            const float4 bk = bkv[h];
            const float bqv = bqh[h];
            vf4 v;
            v.x = (ok0 ? (a.x + bqv + bk.x) : -INFINITY) - p0;  // pen LAST (matches ref rounding)
            v.y = (ok1 ? (a.y + bqv + bk.y) : -INFINITY) - p1;
            v.z = (ok2 ? (a.z + bqv + bk.z) : -INFINITY) - p2;
            v.w = (ok3 ? (a.w + bqv + bk.w) : -INFINITY) - p3;
            __builtin_nontemporal_store(v, (vf4*)(op + (size_t)h*LSEQ*LSEQ));
        }

        // 4. stage next chunk into other buffer; ONE lgkm-only barrier/chunk.
        //    ds_write waits vmcnt for pre[] only (loads older than stores).
        //    Dot-reads of buf cur are anchored before the barrier by the
        //    store dep-chain; writes go to buf^1 -> no WAR race.
        if (c < 15) {
            const int nxt = ((c + 1) & 1) * 8192;
            #pragma unroll
            for (int p = 0; p < 8; ++p) {
                int F = tid + 256*p;
                int r = F >> 4, q16 = F & 15;
                *(float4*)(&kws[nxt + r*64 + 4*(q16 ^ ((r>>2)&15))]) = pre[p];
            }
            asm volatile("s_waitcnt lgkmcnt(0)");
            __builtin_amdgcn_s_barrier();
        }
    }
}

extern "C" void kernel_launch(void* const* d_in, const int* in_sizes, int n_in,
                              void* d_out, int out_size, void* d_ws, size_t ws_size,
                              hipStream_t stream) {
    const float* inputs = (const float*)d_in[0];   // (2,2048,1024)
    const int*   mask   = (const int*)  d_in[1];   // (2,2048)
    const float* Wp     = (const float*)d_in[2];   // (1024,128)
    const float* bp     = (const float*)d_in[3];   // (128,)
    const float* Wq     = (const float*)d_in[4];   // (128,24)
    const float* bq     = (const float*)d_in[5];   // (24,)
    float* out = (float*)d_out;                    // (2,12,2048,2048)

    float* Cp  = (float*)d_ws;                     // KSPLIT * 4096 * 128
    float* qwb = Cp  + (size_t)KSPLIT*MALL*NKV;    // 4096 * 64
    float* kwb = qwb + (size_t)MALL*64;            // 4096 * 64
    float* bQ  = kwb + (size_t)MALL*64;            // 2*12*2048
    float* bK  = bQ  + (size_t)NB*12*LSEQ;         // 2*12*2048

    k1_gemm     <<<dim3(8, 64),   256, 0, stream>>>(inputs, Wp, Cp);
    k2_rope_bias<<<dim3(MALL),     64, 0, stream>>>(Cp, bp, Wq, bq, qwb, kwb, bQ, bK);
    k3_scores   <<<dim3(256, 2), 256, 65536, stream>>>(qwb, kwb, bQ, bK, mask, out);
}

// Round 7
// 478.067 us; speedup vs baseline: 1.0275x; 1.0275x over previous
//
#include <hip/hip_runtime.h>
#include <math.h>

#define LSEQ 2048
#define NB 2
#define HDIM 1024
#define NKV 128          // 2*HEAD_SIZE
#define MALL (NB*LSEQ)   // 4096
#define KSPLIT 4

// ---------------- K1: seq_out partials = inputs @ Wp (K split in 4) --------
__global__ __launch_bounds__(256) void k1_gemm(const float* __restrict__ A,
                                               const float* __restrict__ Wp,
                                               float* __restrict__ Cp) {
    const int nt    = blockIdx.x & 1;
    const int split = blockIdx.x >> 1;
    const int m0 = blockIdx.y * 64;
    const int n0 = nt * 64;
    __shared__ float As[32][68];   // [k][m], pad 68 keeps float4 reads 16B-aligned
    __shared__ float Bs[32][64];   // [k][n]
    const int tid = threadIdx.x;
    const int tm = tid & 15;       // m quad
    const int tn = tid >> 4;       // n quad
    float acc[4][4] = {};
    for (int kc = 0; kc < 8; ++kc) {
        const int k0 = split*256 + kc*32;
        #pragma unroll
        for (int p = 0; p < 2; ++p) {
            int idx = tid + 256*p;          // 0..511
            int row = idx >> 3, kq = idx & 7;
            float4 a = *(const float4*)(A + (size_t)(m0+row)*HDIM + k0 + 4*kq);
            As[4*kq+0][row] = a.x;
            As[4*kq+1][row] = a.y;
            As[4*kq+2][row] = a.z;
            As[4*kq+3][row] = a.w;
        }
        #pragma unroll
        for (int p = 0; p < 2; ++p) {
            int idx = tid + 256*p;
            int r = idx >> 4, c = idx & 15;
            *(float4*)(&Bs[r][4*c]) = *(const float4*)(Wp + (size_t)(k0+r)*NKV + n0 + 4*c);
        }
        __syncthreads();
        #pragma unroll
        for (int kk = 0; kk < 32; ++kk) {
            float4 av = *(const float4*)(&As[kk][4*tm]);
            float4 bv = *(const float4*)(&Bs[kk][4*tn]);
            float aa[4] = {av.x, av.y, av.z, av.w};
            float bb[4] = {bv.x, bv.y, bv.z, bv.w};
            #pragma unroll
            for (int i = 0; i < 4; ++i)
                #pragma unroll
                for (int j = 0; j < 4; ++j)
                    acc[i][j] = fmaf(aa[i], bb[j], acc[i][j]);
        }
        __syncthreads();
    }
    float* outp = Cp + (size_t)split*MALL*NKV;
    #pragma unroll
    for (int i = 0; i < 4; ++i) {
        float4 v = make_float4(acc[i][0], acc[i][1], acc[i][2], acc[i][3]);
        *(float4*)(outp + (size_t)(m0 + 4*tm + i)*NKV + n0 + 4*tn) = v;
    }
}

// ---------------- K2: sum K-splits (+bp), RoPE, bias = seq@Wq/2 ------------
__global__ __launch_bounds__(64) void k2_rope_bias(const float* __restrict__ Cp,
        const float* __restrict__ bp, const float* __restrict__ Wq,
        const float* __restrict__ bq, float* __restrict__ qwout,
        float* __restrict__ kwout, float* __restrict__ biasQ,
        float* __restrict__ biasK) {
    const int row = blockIdx.x;         // 0..4095 (b*L + l)
    const int b = row >> 11;
    const int l = row & (LSEQ - 1);
    const int t = threadIdx.x;          // 0..63 ; lane t owns dims (2t, 2t+1)
    float x0 = bp[2*t], x1 = bp[2*t+1];
    #pragma unroll
    for (int s = 0; s < KSPLIT; ++s) {
        const float* r = Cp + (size_t)s*MALL*NKV + (size_t)row*NKV;
        x0 += r[2*t];
        x1 += r[2*t+1];
    }
    const int p = t & 31;               // pair index within head
    float inv = exp2f(-0.41524101186098287f * (float)p);  // 10000^(-p/32)
    float ang = (float)l * inv;
    float sn = sinf(ang), cs = cosf(ang);
    float y0 = x0*cs - x1*sn;
    float y1 = x1*cs + x0*sn;
    float* dst = (t < 32) ? (qwout + (size_t)row*64) : (kwout + (size_t)row*64);
    dst[2*p]   = y0;
    dst[2*p+1] = y1;
    float res = 0.f;
    for (int j = 0; j < 24; ++j) {
        float part = fmaf(x0, Wq[(2*t)*24 + j], x1 * Wq[(2*t+1)*24 + j]);
        #pragma unroll
        for (int off = 32; off > 0; off >>= 1)
            part += __shfl_xor(part, off);
        if (t == j) res = part;
    }
    if (t < 24) {
        float v = (res + bq[t]) * 0.5f;
        int h = t >> 1;
        float* bb = (t & 1) ? biasK : biasQ;
        bb[((size_t)b*12 + h)*LSEQ + l] = v;
    }
}

// ---------------- K3 v9: champion structure at 2x occupancy ----------------
// grid (1024, 2): x = m-PAIR, y = b. 256 threads; g = tid>>7 (scalarized via
// readfirstlane) owns row m0+g with q in only 64 VGPRs -> fits
// __launch_bounds__(256,4): 4 blocks/CU = 16 waves (vs champion's 8).
// LDS 128x68 = 34 KB x 4 blocks = 136 <= 160 KB. Store pattern, barrier
// protocol, and arithmetic order BYTE-IDENTICAL to the 458 us champion:
// NT dword stores, 2x __syncthreads per chunk, v=(acc+bq+bk); ok?:-INF; -=pen.
// Theory: k3 is VALU/latency-bound at 8 waves/CU, not store-bound (6 failed
// store theories); 16 waves halve exposed barrier+latency cost, and SGPR
// bases (scalar g) kill per-store 64-bit address VALU.
__global__ __launch_bounds__(256, 4) void k3_scores(const float* __restrict__ qw,
        const float* __restrict__ kwv, const float* __restrict__ biasQ,
        const float* __restrict__ biasK, const int* __restrict__ mask,
        float* __restrict__ out) {
    const int m0 = blockIdx.x * 2;
    const int b  = blockIdx.y;
    const int tid = threadIdx.x;
    const int nl = tid & 127;
    const int g  = __builtin_amdgcn_readfirstlane(tid >> 7);  // scalar row select
    __shared__ float kws[128 * 68];     // pad 68: word off 4*(n+j) mod 32 -> even banks

    const size_t rowbase = (size_t)b * LSEQ;
    const int m = m0 + g;               // scalar

    float4 q4[16];
    {
        const float4* qp = (const float4*)(qw + (rowbase + m)*64);
        #pragma unroll
        for (int j = 0; j < 16; ++j) q4[j] = qp[j];
    }
    float bqh[12];
    #pragma unroll
    for (int h = 0; h < 12; ++h) bqh[h] = biasQ[((size_t)b*12 + h)*LSEQ + m];
    const bool okm = mask[rowbase + m] != 0;
    // scalar per-row output base; h-streams at scalar 4M-float stride
    float* const orow = out + ((size_t)b*12*LSEQ + (size_t)m)*LSEQ;
    const float* const bkrow = biasK + (size_t)b*12*LSEQ;

    for (int c = 0; c < 16; ++c) {
        const int nbase = c * 128;
        __syncthreads();                 // guard kws against previous chunk's readers
        #pragma unroll
        for (int p = 0; p < 8; ++p) {
            int f4 = tid + 256*p;        // 0..2047 float4-chunks
            int r = f4 >> 4, q16 = f4 & 15;
            float4 v = *(const float4*)(kwv + (rowbase + nbase + r)*64 + 4*q16);
            *(float4*)(&kws[r*68 + 4*q16]) = v;
        }
        __syncthreads();

        const int n = nbase + nl;
        float acc = 0.f;
        const float4* kr = (const float4*)(&kws[nl * 68]);  // 272B stride: 16B aligned
        #pragma unroll
        for (int j = 0; j < 16; ++j) {
            float4 kv = kr[j];
            float4 qv = q4[j];
            acc = fmaf(qv.x, kv.x, acc);
            acc = fmaf(qv.y, kv.y, acc);
            acc = fmaf(qv.z, kv.z, acc);
            acc = fmaf(qv.w, kv.w, acc);
        }
        acc *= 0.125f;                   // / sqrt(64)

        const bool okn = mask[rowbase + n] != 0;
        const float pen = (m > n) ? 1e12f : 0.f;
        const bool ok = okm && okn;
        #pragma unroll
        for (int h = 0; h < 12; ++h) {
            float bk = bkrow[(size_t)h*LSEQ + n];
            float v = acc + bqh[h] + bk; // exact champion rounding order
            v = ok ? v : -INFINITY;
            v -= pen;
            __builtin_nontemporal_store(v, orow + (size_t)h*LSEQ*LSEQ + n);
        }
    }
}

extern "C" void kernel_launch(void* const* d_in, const int* in_sizes, int n_in,
                              void* d_out, int out_size, void* d_ws, size_t ws_size,
                              hipStream_t stream) {
    const float* inputs = (const float*)d_in[0];   // (2,2048,1024)
    const int*   mask   = (const int*)  d_in[1];   // (2,2048)
    const float* Wp     = (const float*)d_in[2];   // (1024,128)
    const float* bp     = (const float*)d_in[3];   // (128,)
    const float* Wq     = (const float*)d_in[4];   // (128,24)
    const float* bq     = (const float*)d_in[5];   // (24,)
    float* out = (float*)d_out;                    // (2,12,2048,2048)

    float* Cp  = (float*)d_ws;                     // KSPLIT * 4096 * 128
    float* qwb = Cp  + (size_t)KSPLIT*MALL*NKV;    // 4096 * 64
    float* kwb = qwb + (size_t)MALL*64;            // 4096 * 64
    float* bQ  = kwb + (size_t)MALL*64;            // 2*12*2048
    float* bK  = bQ  + (size_t)NB*12*LSEQ;         // 2*12*2048

    k1_gemm     <<<dim3(8, 64),    256, 0, stream>>>(inputs, Wp, Cp);
    k2_rope_bias<<<dim3(MALL),      64, 0, stream>>>(Cp, bp, Wq, bq, qwb, kwb, bQ, bK);
    k3_scores   <<<dim3(1024, 2), 256, 0, stream>>>(qwb, kwb, bQ, bK, mask, out);
}

// Round 8
// 466.196 us; speedup vs baseline: 1.0537x; 1.0255x over previous
//
#include <hip/hip_runtime.h>
#include <math.h>

#define LSEQ 2048
#define NB 2
#define HDIM 1024
#define NKV 128          // 2*HEAD_SIZE
#define MALL (NB*LSEQ)   // 4096
#define KSPLIT 4

typedef float vf4 __attribute__((ext_vector_type(4)));  // native vector: NT-storable

// ---------------- K1: seq_out partials = inputs @ Wp (K split in 4) --------
__global__ __launch_bounds__(256) void k1_gemm(const float* __restrict__ A,
                                               const float* __restrict__ Wp,
                                               float* __restrict__ Cp) {
    const int nt    = blockIdx.x & 1;
    const int split = blockIdx.x >> 1;
    const int m0 = blockIdx.y * 64;
    const int n0 = nt * 64;
    __shared__ float As[32][68];   // [k][m], pad 68 keeps float4 reads 16B-aligned
    __shared__ float Bs[32][64];   // [k][n]
    const int tid = threadIdx.x;
    const int tm = tid & 15;       // m quad
    const int tn = tid >> 4;       // n quad
    float acc[4][4] = {};
    for (int kc = 0; kc < 8; ++kc) {
        const int k0 = split*256 + kc*32;
        #pragma unroll
        for (int p = 0; p < 2; ++p) {
            int idx = tid + 256*p;          // 0..511
            int row = idx >> 3, kq = idx & 7;
            float4 a = *(const float4*)(A + (size_t)(m0+row)*HDIM + k0 + 4*kq);
            As[4*kq+0][row] = a.x;
            As[4*kq+1][row] = a.y;
            As[4*kq+2][row] = a.z;
            As[4*kq+3][row] = a.w;
        }
        #pragma unroll
        for (int p = 0; p < 2; ++p) {
            int idx = tid + 256*p;
            int r = idx >> 4, c = idx & 15;
            *(float4*)(&Bs[r][4*c]) = *(const float4*)(Wp + (size_t)(k0+r)*NKV + n0 + 4*c);
        }
        __syncthreads();
        #pragma unroll
        for (int kk = 0; kk < 32; ++kk) {
            float4 av = *(const float4*)(&As[kk][4*tm]);
            float4 bv = *(const float4*)(&Bs[kk][4*tn]);
            float aa[4] = {av.x, av.y, av.z, av.w};
            float bb[4] = {bv.x, bv.y, bv.z, bv.w};
            #pragma unroll
            for (int i = 0; i < 4; ++i)
                #pragma unroll
                for (int j = 0; j < 4; ++j)
                    acc[i][j] = fmaf(aa[i], bb[j], acc[i][j]);
        }
        __syncthreads();
    }
    float* outp = Cp + (size_t)split*MALL*NKV;
    #pragma unroll
    for (int i = 0; i < 4; ++i) {
        float4 v = make_float4(acc[i][0], acc[i][1], acc[i][2], acc[i][3]);
        *(float4*)(outp + (size_t)(m0 + 4*tm + i)*NKV + n0 + 4*tn) = v;
    }
}

// ---------------- K2: sum K-splits (+bp), RoPE, bias = seq@Wq/2 ------------
__global__ __launch_bounds__(64) void k2_rope_bias(const float* __restrict__ Cp,
        const float* __restrict__ bp, const float* __restrict__ Wq,
        const float* __restrict__ bq, float* __restrict__ qwout,
        float* __restrict__ kwout, float* __restrict__ biasQ,
        float* __restrict__ biasK) {
    const int row = blockIdx.x;         // 0..4095 (b*L + l)
    const int b = row >> 11;
    const int l = row & (LSEQ - 1);
    const int t = threadIdx.x;          // 0..63 ; lane t owns dims (2t, 2t+1)
    float x0 = bp[2*t], x1 = bp[2*t+1];
    #pragma unroll
    for (int s = 0; s < KSPLIT; ++s) {
        const float* r = Cp + (size_t)s*MALL*NKV + (size_t)row*NKV;
        x0 += r[2*t];
        x1 += r[2*t+1];
    }
    const int p = t & 31;               // pair index within head
    float inv = exp2f(-0.41524101186098287f * (float)p);  // 10000^(-p/32)
    float ang = (float)l * inv;
    float sn = sinf(ang), cs = cosf(ang);
    float y0 = x0*cs - x1*sn;
    float y1 = x1*cs + x0*sn;
    float* dst = (t < 32) ? (qwout + (size_t)row*64) : (kwout + (size_t)row*64);
    dst[2*p]   = y0;
    dst[2*p+1] = y1;
    float res = 0.f;
    for (int j = 0; j < 24; ++j) {
        float part = fmaf(x0, Wq[(2*t)*24 + j], x1 * Wq[(2*t+1)*24 + j]);
        #pragma unroll
        for (int off = 32; off > 0; off >>= 1)
            part += __shfl_xor(part, off);
        if (t == j) res = part;
    }
    if (t < 24) {
        float v = (res + bq[t]) * 0.5f;
        int h = t >> 1;
        float* bb = (t & 1) ? biasK : biasQ;
        bb[((size_t)b*12 + h)*LSEQ + l] = v;
    }
}

// ---------------- K3 v10: scores -> LDS, then 32KB-contiguous NT bursts ----
// grid (512, 2): x = m-tile (4 rows), y = b. 256 threads, 2 blocks/CU.
// Phase 1 (16 chunks, champion structure): stage kw 128-n chunk -> LDS,
//   dot q{2g,2g+1}.k[n] -> raw*0.125 scores into 32 KB LDS buffer ss[4][2048]
//   (ds_write instead of 12 strided global stores).
// Phase 2: fan-out from LDS: for each h, one CONTIGUOUS 32 KB ascending NT
//   float4 burst (4 rows x 8 KB, rows adjacent in memory). Write-run length
//   x128 vs champion's 256 B stream rotation; zero extra HBM traffic.
// Arithmetic order byte-matches champion: s=acc*0.125 (exact in LDS);
// v=s+bq+bk; v=ok?v:-INF; v-=pen.
__global__ __launch_bounds__(256, 2) void k3_scores(const float* __restrict__ qw,
        const float* __restrict__ kwv, const float* __restrict__ biasQ,
        const float* __restrict__ biasK, const int* __restrict__ mask,
        float* __restrict__ out) {
    const int m0 = blockIdx.x * 4;
    const int b  = blockIdx.y;
    const int tid = threadIdx.x;
    const int nl = tid & 127;
    const int g  = tid >> 7;            // 0/1 -> m rows 2g, 2g+1
    __shared__ float kws[128 * 68];     // 34 KB staging, pad 68
    __shared__ float ss[4 * LSEQ];      // 32 KB raw scores (x0.125)
    __shared__ float bql[48];           // biasQ[h][r], h<12, r<4

    const size_t rowbase = (size_t)b * LSEQ;
    const int mA = m0 + 2*g, mB = mA + 1;

    float4 q0[16], q1[16];
    {
        const float4* qp0 = (const float4*)(qw + (rowbase + mA)*64);
        const float4* qp1 = (const float4*)(qw + (rowbase + mB)*64);
        #pragma unroll
        for (int j = 0; j < 16; ++j) { q0[j] = qp0[j]; q1[j] = qp1[j]; }
    }
    if (tid < 48) {
        int h = tid >> 2, r = tid & 3;
        bql[tid] = biasQ[((size_t)b*12 + h)*LSEQ + m0 + r];
    }

    // ---------- phase 1: all scores for 4 rows into LDS ----------
    for (int c = 0; c < 16; ++c) {
        const int nbase = c * 128;
        __syncthreads();                 // guard kws against previous chunk's readers
        #pragma unroll
        for (int p = 0; p < 8; ++p) {
            int f4 = tid + 256*p;        // 0..2047 float4-chunks
            int r = f4 >> 4, q16 = f4 & 15;
            float4 v = *(const float4*)(kwv + (rowbase + nbase + r)*64 + 4*q16);
            *(float4*)(&kws[r*68 + 4*q16]) = v;
        }
        __syncthreads();

        const int n = nbase + nl;
        float acc0 = 0.f, acc1 = 0.f;
        const float4* kr = (const float4*)(&kws[nl * 68]);  // 272B stride
        #pragma unroll
        for (int j = 0; j < 16; ++j) {
            float4 kv = kr[j];
            acc0 = fmaf(q0[j].x, kv.x, acc0);
            acc0 = fmaf(q0[j].y, kv.y, acc0);
            acc0 = fmaf(q0[j].z, kv.z, acc0);
            acc0 = fmaf(q0[j].w, kv.w, acc0);
            acc1 = fmaf(q1[j].x, kv.x, acc1);
            acc1 = fmaf(q1[j].y, kv.y, acc1);
            acc1 = fmaf(q1[j].z, kv.z, acc1);
            acc1 = fmaf(q1[j].w, kv.w, acc1);
        }
        ss[2*g*LSEQ + n]     = acc0 * 0.125f;
        ss[(2*g+1)*LSEQ + n] = acc1 * 0.125f;
    }
    __syncthreads();                     // ss complete & visible

    // ---------- phase 2: per-head contiguous 32 KB NT bursts ----------
    // mask/okm reused across heads
    bool okm[4];
    #pragma unroll
    for (int r = 0; r < 4; ++r) okm[r] = mask[rowbase + m0 + r] != 0;
    const int nA = 4*tid, nB = 4*tid + 1024;   // n within a row-half
    const int4 mqA = *(const int4*)(mask + rowbase + nA);
    const int4 mqB = *(const int4*)(mask + rowbase + nB);
    const float* bkb = biasK + (size_t)b*12*LSEQ;
    float* const ob = out + ((size_t)b*12*LSEQ + (size_t)m0)*LSEQ;

    #pragma unroll
    for (int h = 0; h < 12; ++h) {
        const float4 bkA = *(const float4*)(bkb + (size_t)h*LSEQ + nA);
        const float4 bkB = *(const float4*)(bkb + (size_t)h*LSEQ + nB);
        float* const oh = ob + (size_t)h*LSEQ*LSEQ;   // 4 rows contiguous (32 KB)
        #pragma unroll
        for (int r = 0; r < 4; ++r) {
            const float bqv = bql[h*4 + r];
            const int m = m0 + r;
            const bool om = okm[r];
            // half A: words r*2048 + nA
            {
                float4 s = *(const float4*)(&ss[r*LSEQ + nA]);
                vf4 v;
                float t;
                t = s.x + bqv + bkA.x; t = (om && mqA.x) ? t : -INFINITY; v.x = t - ((m > nA+0) ? 1e12f : 0.f);
                t = s.y + bqv + bkA.y; t = (om && mqA.y) ? t : -INFINITY; v.y = t - ((m > nA+1) ? 1e12f : 0.f);
                t = s.z + bqv + bkA.z; t = (om && mqA.z) ? t : -INFINITY; v.z = t - ((m > nA+2) ? 1e12f : 0.f);
                t = s.w + bqv + bkA.w; t = (om && mqA.w) ? t : -INFINITY; v.w = t - ((m > nA+3) ? 1e12f : 0.f);
                __builtin_nontemporal_store(v, (vf4*)(oh + (size_t)r*LSEQ + nA));
            }
            // half B: words r*2048 + nB
            {
                float4 s = *(const float4*)(&ss[r*LSEQ + nB]);
                vf4 v;
                float t;
                t = s.x + bqv + bkB.x; t = (om && mqB.x) ? t : -INFINITY; v.x = t - ((m > nB+0) ? 1e12f : 0.f);
                t = s.y + bqv + bkB.y; t = (om && mqB.y) ? t : -INFINITY; v.y = t - ((m > nB+1) ? 1e12f : 0.f);
                t = s.z + bqv + bkB.z; t = (om && mqB.z) ? t : -INFINITY; v.z = t - ((m > nB+2) ? 1e12f : 0.f);
                t = s.w + bqv + bkB.w; t = (om && mqB.w) ? t : -INFINITY; v.w = t - ((m > nB+3) ? 1e12f : 0.f);
                __builtin_nontemporal_store(v, (vf4*)(oh + (size_t)r*LSEQ + nB));
            }
        }
    }
}

extern "C" void kernel_launch(void* const* d_in, const int* in_sizes, int n_in,
                              void* d_out, int out_size, void* d_ws, size_t ws_size,
                              hipStream_t stream) {
    const float* inputs = (const float*)d_in[0];   // (2,2048,1024)
    const int*   mask   = (const int*)  d_in[1];   // (2,2048)
    const float* Wp     = (const float*)d_in[2];   // (1024,128)
    const float* bp     = (const float*)d_in[3];   // (128,)
    const float* Wq     = (const float*)d_in[4];   // (128,24)
    const float* bq     = (const float*)d_in[5];   // (24,)
    float* out = (float*)d_out;                    // (2,12,2048,2048)

    float* Cp  = (float*)d_ws;                     // KSPLIT * 4096 * 128
    float* qwb = Cp  + (size_t)KSPLIT*MALL*NKV;    // 4096 * 64
    float* kwb = qwb + (size_t)MALL*64;            // 4096 * 64
    float* bQ  = kwb + (size_t)MALL*64;            // 2*12*2048
    float* bK  = bQ  + (size_t)NB*12*LSEQ;         // 2*12*2048

    k1_gemm     <<<dim3(8, 64),   256, 0, stream>>>(inputs, Wp, Cp);
    k2_rope_bias<<<dim3(MALL),     64, 0, stream>>>(Cp, bp, Wq, bq, qwb, kwb, bQ, bK);
    k3_scores   <<<dim3(512, 2), 256, 0, stream>>>(qwb, kwb, bQ, bK, mask, out);
}